// Round 2
// baseline (289.665 us; speedup 1.0000x reference)
//
#include <hip/hip_runtime.h>

#define F 8
#define L 16
#define XN 8
#define YN 4
#define NS 4
#define BLK 256

// out layout: [L*N] (norm.T) followed by [YN*N] (out.T)
__global__ __launch_bounds__(256) void eafnn_kernel(
    const float* __restrict__ inp,
    const float* __restrict__ x,
    const float* __restrict__ c,
    const float* __restrict__ b,
    const float* __restrict__ w,
    float* __restrict__ out,
    int n_total)
{
    // Polynomial form of the log2-domain Gaussian:
    //   k*d^2 = A*v^2 + B*v + C,  A = k = -log2(e)/(2b^2), B = -2kc, C = kc^2
    __shared__ __attribute__((aligned(16))) float s_A[F * L];
    __shared__ __attribute__((aligned(16))) float s_B[F * L];
    __shared__ __attribute__((aligned(16))) float s_Cp[F * L];
    __shared__ __attribute__((aligned(16))) float s_C0[L];
    __shared__ __attribute__((aligned(16))) float s_w[L * XN * YN];

    const int tid = threadIdx.x;
    if (tid < F * L) {
        float bb = b[tid], cc = c[tid];
        float k = -1.4426950408889634f / (2.0f * bb * bb);
        s_A[tid] = k;
        s_B[tid] = -2.0f * k * cc;
        s_Cp[tid] = k * cc * cc;
    }
    for (int i = tid; i < L * XN * YN; i += BLK) s_w[i] = w[i];
    __syncthreads();
    if (tid < L) {
        float a = 0.0f;
#pragma unroll
        for (int f = 0; f < F; ++f) a += s_Cp[f * L + tid];
        s_C0[tid] = a;
    }
    __syncthreads();

    const int n0 = blockIdx.x * (BLK * NS) + tid;

    int nn[NS];
    bool valid[NS];
#pragma unroll
    for (int s = 0; s < NS; ++s) {
        int n = n0 + s * BLK;
        valid[s] = (n < n_total);
        nn[s] = valid[s] ? n : (n_total - 1);
    }

    // ---- coalesced input loads (clamped for tail) ----
    float fi[NS][F], xv[NS][XN];
#pragma unroll
    for (int s = 0; s < NS; ++s) {
        const float4* ip = (const float4*)(inp + (size_t)nn[s] * F);
        float4 a0 = ip[0], a1 = ip[1];
        fi[s][0] = a0.x; fi[s][1] = a0.y; fi[s][2] = a0.z; fi[s][3] = a0.w;
        fi[s][4] = a1.x; fi[s][5] = a1.y; fi[s][6] = a1.z; fi[s][7] = a1.w;
        const float4* xp = (const float4*)(x + (size_t)nn[s] * XN);
        float4 b0 = xp[0], b1 = xp[1];
        xv[s][0] = b0.x; xv[s][1] = b0.y; xv[s][2] = b0.z; xv[s][3] = b0.w;
        xv[s][4] = b1.x; xv[s][5] = b1.y; xv[s][6] = b1.z; xv[s][7] = b1.w;
    }

    // ---- membership accumulation, tables-outer / samples-inner ----
    float sacc[NS][L];
#pragma unroll
    for (int lq = 0; lq < L / 4; ++lq) {
        float4 cq = *(const float4*)&s_C0[lq * 4];
#pragma unroll
        for (int s = 0; s < NS; ++s) {
            sacc[s][lq * 4 + 0] = cq.x;
            sacc[s][lq * 4 + 1] = cq.y;
            sacc[s][lq * 4 + 2] = cq.z;
            sacc[s][lq * 4 + 3] = cq.w;
        }
    }

#pragma unroll
    for (int f = 0; f < F; ++f) {
        float v[NS], v2[NS];
#pragma unroll
        for (int s = 0; s < NS; ++s) { v[s] = fi[s][f]; v2[s] = v[s] * v[s]; }
#pragma unroll
        for (int lq = 0; lq < L / 4; ++lq) {
            float4 Aq = *(const float4*)&s_A[f * L + lq * 4];
            float4 Bq = *(const float4*)&s_B[f * L + lq * 4];
#pragma unroll
            for (int s = 0; s < NS; ++s) {
                sacc[s][lq * 4 + 0] = fmaf(Aq.x, v2[s], fmaf(Bq.x, v[s], sacc[s][lq * 4 + 0]));
                sacc[s][lq * 4 + 1] = fmaf(Aq.y, v2[s], fmaf(Bq.y, v[s], sacc[s][lq * 4 + 1]));
                sacc[s][lq * 4 + 2] = fmaf(Aq.z, v2[s], fmaf(Bq.z, v[s], sacc[s][lq * 4 + 2]));
                sacc[s][lq * 4 + 3] = fmaf(Aq.w, v2[s], fmaf(Bq.w, v[s], sacc[s][lq * 4 + 3]));
            }
        }
    }

    // ---- firing + normalization + norm.T store ----
#pragma unroll
    for (int s = 0; s < NS; ++s) {
        float fr[L];
        float tot = 0.0f;
#pragma unroll
        for (int l = 0; l < L; ++l) {
            fr[l] = __builtin_amdgcn_exp2f(sacc[s][l]) + 0.001f;
            tot += fr[l];
        }
        float inv = 1.0f / tot;
#pragma unroll
        for (int l = 0; l < L; ++l) {
            float nl = fr[l] * inv;
            sacc[s][l] = nl;                       // reuse as norm
            if (valid[s]) out[(size_t)l * n_total + nn[s]] = nl;
        }
    }

    // ---- consequents: rule_out per l, w quads amortized over samples ----
    float acc[NS][YN];
#pragma unroll
    for (int s = 0; s < NS; ++s)
#pragma unroll
        for (int y = 0; y < YN; ++y) acc[s][y] = 0.0f;

#pragma unroll
    for (int l = 0; l < L; ++l) {
        float4 wq[XN];   // quad i = w[l, x=i, 0..3] since YN==4
#pragma unroll
        for (int i = 0; i < XN; ++i) wq[i] = *(const float4*)&s_w[l * XN * YN + i * 4];
#pragma unroll
        for (int s = 0; s < NS; ++s) {
            float r0 = 0.f, r1 = 0.f, r2 = 0.f, r3 = 0.f;
#pragma unroll
            for (int i = 0; i < XN; ++i) {
                float xs = xv[s][i];
                r0 = fmaf(xs, wq[i].x, r0);
                r1 = fmaf(xs, wq[i].y, r1);
                r2 = fmaf(xs, wq[i].z, r2);
                r3 = fmaf(xs, wq[i].w, r3);
            }
            float nl = sacc[s][l];
            acc[s][0] = fmaf(nl, r0, acc[s][0]);
            acc[s][1] = fmaf(nl, r1, acc[s][1]);
            acc[s][2] = fmaf(nl, r2, acc[s][2]);
            acc[s][3] = fmaf(nl, r3, acc[s][3]);
        }
    }

    float* out_y = out + (size_t)L * n_total;
#pragma unroll
    for (int s = 0; s < NS; ++s) {
        if (valid[s]) {
#pragma unroll
            for (int y = 0; y < YN; ++y)
                out_y[(size_t)y * n_total + nn[s]] = acc[s][y];
        }
    }
}

extern "C" void kernel_launch(void* const* d_in, const int* in_sizes, int n_in,
                              void* d_out, int out_size, void* d_ws, size_t ws_size,
                              hipStream_t stream) {
    const float* inp = (const float*)d_in[0];
    const float* x   = (const float*)d_in[1];
    const float* c   = (const float*)d_in[2];
    const float* b   = (const float*)d_in[3];
    const float* w   = (const float*)d_in[4];
    float* out = (float*)d_out;

    int n_total = in_sizes[0] / F;   // 500000
    int grid = (n_total + BLK * NS - 1) / (BLK * NS);
    eafnn_kernel<<<grid, BLK, 0, stream>>>(inp, x, c, b, w, out, n_total);
}